// Round 2
// baseline (8465.955 us; speedup 1.0000x reference)
//
#include <hip/hip_runtime.h>
#include <hip/hip_bf16.h>

#define EDIM 1024
#define MDIM 4096
#define SEQ  2048
#define NB   4
#define ROWS 8192

__device__ __forceinline__ float bf2f(unsigned short u) {
    return __uint_as_float(((unsigned int)u) << 16);
}
__device__ __forceinline__ void ld4f(const float* __restrict__ p, float* d) {
    const float4 v = *reinterpret_cast<const float4*>(p);
    d[0] = v.x; d[1] = v.y; d[2] = v.z; d[3] = v.w;
}
__device__ __forceinline__ void ld4h(const unsigned short* __restrict__ p, float* d) {
    const ushort4 v = *reinterpret_cast<const ushort4*>(p);
    d[0] = bf2f(v.x); d[1] = bf2f(v.y); d[2] = bf2f(v.z); d[3] = bf2f(v.w);
}

// dtype sniffer: flag=1 -> inputs are bf16, flag=0 -> f32
__global__ __launch_bounds__(64)
void sniff_k(const unsigned int* __restrict__ w, int* __restrict__ flag) {
    int ok = 0;
    const int base = threadIdx.x * 32;
#pragma unroll
    for (int i = 0; i < 32; ++i) {
        const unsigned int v = w[base + i];
        const unsigned int lo = v & 0xFFFFu, hi = v >> 16;
        const unsigned int el = (lo >> 7) & 0xFF, eh = (hi >> 7) & 0xFF;
        const bool okl = (lo == 0u) || (el >= 0x30u && el <= 0x7Eu);
        const bool okh = (hi == 0u) || (eh >= 0x30u && eh <= 0x7Eu);
        ok += (okl && okh) ? 1 : 0;
    }
#pragma unroll
    for (int off = 32; off > 0; off >>= 1) ok += __shfl_down(ok, off);
    if (threadIdx.x == 0) *flag = (ok > 1400) ? 1 : 0;
}

__global__ __launch_bounds__(256)
void gather_k(const int* __restrict__ x, const void* __restrict__ emb,
              float* __restrict__ h, const int* __restrict__ flagp) {
    const int bf = *flagp;
    const long long row = blockIdx.x;
    const int idx = x[row];
    const long long off = (long long)idx * EDIM + threadIdx.x * 4;
    float d[4];
    if (bf) ld4h((const unsigned short*)emb + off, d);
    else    ld4f((const float*)emb + off, d);
    *reinterpret_cast<float4*>(h + row * EDIM + threadIdx.x * 4)
        = make_float4(d[0], d[1], d[2], d[3]);
}

// C[M,N] = op(A[M,K] @ B + bias). NT: B is [N,K] (C=A@B^T), else [K,N].
// bBase: element offset added to B (layer select). bF/cF: B,bias / C dtype
// follow the runtime input flag (bf16 if flag=1) vs always-f32.
template<bool NT, bool BIAS, bool RELU, bool MASK>
__global__ __launch_bounds__(256)
void gemm_k(const float* __restrict__ A, const void* __restrict__ Bv,
            const void* __restrict__ biasv, void* __restrict__ Cv,
            int M, int N, int K,
            long long sA, long long sB, long long sC,
            long long bBase, long long biasBase, float scale,
            const int* __restrict__ flagp, int bF, int cF) {
    const int flag = *flagp;
    const int bfB = bF ? flag : 0;
    const int bfC = cF ? flag : 0;

    A += (long long)blockIdx.z * sA;
    const long long zB = bBase + (long long)blockIdx.z * sB;
    const long long zC = (long long)blockIdx.z * sC;

    const int brow = blockIdx.y * 128;
    const int bcol = blockIdx.x * 128;
    const int tid  = threadIdx.x;
    const int tx   = tid & 15;
    const int ty   = tid >> 4;

    __shared__ float As[8][128];
    __shared__ float Bs[8][132];

    float acc[8][8];
#pragma unroll
    for (int i = 0; i < 8; ++i)
#pragma unroll
        for (int j = 0; j < 8; ++j) acc[i][j] = 0.f;

    const int lr = tid >> 1;
    const int lk = (tid & 1) * 4;
    const int bn_r = tid >> 5;
    const int bn_c = (tid & 31) * 4;

    long long aoff  = (long long)(brow + lr) * K + lk;
    long long boffT = zB + (long long)(bcol + lr) * K + lk;
    long long boffN = zB + (long long)bn_r * N + bcol + bn_c;

    for (int k0 = 0; k0 < K; k0 += 8) {
        float av[4];
        ld4f(A + aoff, av);
#pragma unroll
        for (int t = 0; t < 4; ++t) As[lk + t][lr] = av[t];

        float bv[4];
        if (NT) {
            if (bfB) ld4h((const unsigned short*)Bv + boffT, bv);
            else     ld4f((const float*)Bv + boffT, bv);
#pragma unroll
            for (int t = 0; t < 4; ++t) Bs[lk + t][lr] = bv[t];
        } else {
            if (bfB) ld4h((const unsigned short*)Bv + boffN, bv);
            else     ld4f((const float*)Bv + boffN, bv);
#pragma unroll
            for (int t = 0; t < 4; ++t) Bs[bn_r][bn_c + t] = bv[t];
        }
        __syncthreads();

#pragma unroll
        for (int kk = 0; kk < 8; ++kk) {
            float a[8], bb[8];
#pragma unroll
            for (int i = 0; i < 8; ++i) a[i] = As[kk][ty * 8 + i];
#pragma unroll
            for (int j = 0; j < 8; ++j) bb[j] = Bs[kk][tx * 8 + j];
#pragma unroll
            for (int i = 0; i < 8; ++i)
#pragma unroll
                for (int j = 0; j < 8; ++j) acc[i][j] = fmaf(a[i], bb[j], acc[i][j]);
        }
        __syncthreads();

        aoff += 8;
        if (NT) boffT += 8; else boffN += (long long)8 * N;
    }

    float bvals[8];
    if (BIAS) {
#pragma unroll
        for (int j = 0; j < 8; ++j) {
            const long long c = biasBase + bcol + tx * 8 + j;
            bvals[j] = bfB ? bf2f(((const unsigned short*)biasv)[c])
                           : ((const float*)biasv)[c];
        }
    }

#pragma unroll
    for (int i = 0; i < 8; ++i) {
        const int r = brow + ty * 8 + i;
#pragma unroll
        for (int j = 0; j < 8; ++j) {
            const int c = bcol + tx * 8 + j;
            float v = acc[i][j];
            if (BIAS) v += bvals[j];
            if (MASK) v = (c >= r) ? v * scale : -1e30f;
            if (RELU) v = fmaxf(v, 0.f);
            const long long off = zC + (long long)r * N + c;
            if (bfC) ((__hip_bfloat16*)Cv)[off] = __float2bfloat16(v);
            else     ((float*)Cv)[off] = v;
        }
    }
}

__global__ __launch_bounds__(256)
void softmax_k(float* __restrict__ Sc) {
    float* row = Sc + (long long)blockIdx.y * SEQ * SEQ + (long long)blockIdx.x * SEQ;
    const int tid = threadIdx.x;

    float v[8];
    float m = -1e30f;
#pragma unroll
    for (int i = 0; i < 8; ++i) { v[i] = row[tid + i * 256]; m = fmaxf(m, v[i]); }
#pragma unroll
    for (int off = 32; off > 0; off >>= 1) m = fmaxf(m, __shfl_down(m, off));

    __shared__ float sm[4];
    __shared__ float ss[4];
    const int wid = tid >> 6, lane = tid & 63;
    if (lane == 0) sm[wid] = m;
    __syncthreads();
    const float mAll = fmaxf(fmaxf(sm[0], sm[1]), fmaxf(sm[2], sm[3]));

    float s = 0.f;
#pragma unroll
    for (int i = 0; i < 8; ++i) { v[i] = __expf(v[i] - mAll); s += v[i]; }
#pragma unroll
    for (int off = 32; off > 0; off >>= 1) s += __shfl_down(s, off);
    if (lane == 0) ss[wid] = s;
    __syncthreads();
    const float inv = 1.f / (ss[0] + ss[1] + ss[2] + ss[3]);
#pragma unroll
    for (int i = 0; i < 8; ++i) row[tid + i * 256] = v[i] * inv;
}

extern "C" void kernel_launch(void* const* d_in, const int* in_sizes, int n_in,
                              void* d_out, int out_size, void* d_ws, size_t ws_size,
                              hipStream_t stream) {
    const int*  x   = (const int*)d_in[0];
    const void* emb = d_in[1];
    const void* Wq  = d_in[2];
    const void* bq  = d_in[3];
    const void* Wk  = d_in[4];
    const void* bk  = d_in[5];
    const void* Wv  = d_in[6];
    const void* bv  = d_in[7];
    const void* W1  = d_in[8];
    const void* b1  = d_in[9];
    const void* W2  = d_in[10];
    const void* b2  = d_in[11];

    char* ws = (char*)d_ws;
    const long long SZ = 33554432LL;  // 8192*1024*4 bytes
    float* h    = (float*)(ws);
    float* q    = (float*)(ws + SZ);
    float* kx   = (float*)(ws + 2 * SZ);
    float* vx   = (float*)(ws + 3 * SZ);
    float* sc   = (float*)(ws + 4 * SZ);
    float* att  = (float*)(ws + 6 * SZ);
    float* mid  = h;
    float* pong = sc;
    int*   flag = (int*)(ws + 7 * SZ);

    const dim3 blk(256);
    const long long SE = (long long)SEQ * EDIM;
    const long long SS = (long long)SEQ * SEQ;

    sniff_k<<<1, 64, 0, stream>>>((const unsigned int*)emb, flag);
    gather_k<<<ROWS, blk, 0, stream>>>(x, emb, h, flag);

    gemm_k<false, true, false, false><<<dim3(8, 64, 1), blk, 0, stream>>>(
        h, Wq, bq, q, ROWS, EDIM, EDIM, 0, 0, 0, 0, 0, 1.f, flag, 1, 0);
    gemm_k<false, true, false, false><<<dim3(8, 64, 1), blk, 0, stream>>>(
        h, Wk, bk, kx, ROWS, EDIM, EDIM, 0, 0, 0, 0, 0, 1.f, flag, 1, 0);
    gemm_k<false, true, false, false><<<dim3(8, 64, 1), blk, 0, stream>>>(
        h, Wv, bv, vx, ROWS, EDIM, EDIM, 0, 0, 0, 0, 0, 1.f, flag, 1, 0);

    gemm_k<true, false, false, true><<<dim3(16, 16, NB), blk, 0, stream>>>(
        q, kx, nullptr, sc, SEQ, SEQ, EDIM, SE, SE, SS, 0, 0, 0.03125f, flag, 0, 0);

    softmax_k<<<dim3(SEQ, NB), blk, 0, stream>>>(sc);

    gemm_k<false, false, true, false><<<dim3(8, 16, NB), blk, 0, stream>>>(
        sc, vx, nullptr, att, SEQ, EDIM, SEQ, SS, SE, SE, 0, 0, 1.f, flag, 0, 0);

    const float* cur = att;
    for (int i = 0; i < 4; ++i) {
        const long long w1off = (long long)i * EDIM * MDIM;
        const long long w2off = (long long)i * MDIM * EDIM;
        const long long b1off = (long long)i * MDIM;
        const long long b2off = (long long)i * EDIM;

        gemm_k<false, true, true, false><<<dim3(32, 64, 1), blk, 0, stream>>>(
            cur, W1, b1, mid, ROWS, MDIM, EDIM,
            0, 0, 0, w1off, b1off, 1.f, flag, 1, 0);

        if (i < 3) {
            float* out = (cur == att) ? pong : att;
            gemm_k<false, true, true, false><<<dim3(8, 64, 1), blk, 0, stream>>>(
                mid, W2, b2, out, ROWS, EDIM, MDIM,
                0, 0, 0, w2off, b2off, 1.f, flag, 1, 0);
            cur = out;
        } else {
            gemm_k<false, true, true, false><<<dim3(8, 64, 1), blk, 0, stream>>>(
                mid, W2, b2, d_out, ROWS, EDIM, MDIM,
                0, 0, 0, w2off, b2off, 1.f, flag, 1, 1);
        }
    }
}